// Round 11
// baseline (303.918 us; speedup 1.0000x reference)
//
#include <hip/hip_runtime.h>

// LightGCN propagation on MI355X — CSR-gather, separable-norm, binned CSR
// build, fp16 state, fused final, 8-lane-per-node gather.
// N = 150000 nodes, D = 64, E = 1.2M edges, 4 layers.
// z = dinv .* emb (fp16). Layers 1-3 write z_l only; layer 4 fused with
// final:  acc = emb0/25 + (z1+z2+z3+z4_inreg) * sqrtdeg/25  (pure write).
// Gather: 8 lanes/node, 16 B fp16 slice per lane — halves load+shuffle
// instruction count vs 16-lane and matches mean degree 8 (full lane util).
// LESSON (r9): grid.sync() costs ~200us/sync on 8-XCD MI355X — never.
//   (binscan fusion below uses a last-block TAIL, not a barrier.)
// LESSON (r4): no nontemporal stores on random scatters.

#define DIMH 64
#define BLK 256
#define BSHIFT 9                    // 512 nodes per bucket
#define BNODES 512
#define EB 8192                     // edges per binscatter block
#define HISTGRID 512

typedef float    f4  __attribute__((ext_vector_type(4)));
typedef float    f8  __attribute__((ext_vector_type(8)));
typedef _Float16 h4  __attribute__((ext_vector_type(4)));
typedef _Float16 h8  __attribute__((ext_vector_type(8)));

__device__ inline f4 cvt4(h4 v) { return __builtin_convertvector(v, f4); }
__device__ inline f8 cvt8(h8 v) { return __builtin_convertvector(v, f8); }

// ---------------------------------------------------------------------------
// init: z0(h16) = concat(user, item); bucketCnt[0..1024) = 0 (incl. the
// done-counter slot used by k_binhistscan's last-block tail).
__global__ void k_init(const float* __restrict__ uemb, const float* __restrict__ iemb,
                       _Float16* __restrict__ z0, int* __restrict__ bucketCnt,
                       long uElems, long totalElems) {
    long t = (long)blockIdx.x * BLK + threadIdx.x;
    if (t < 1024) bucketCnt[t] = 0;
    long base = t * 4;
    if (base >= totalElems) return;
    f4 v = (base < uElems) ? *(const f4*)(uemb + base)
                           : *(const f4*)(iemb + (base - uElems));
    *(h4*)(z0 + base) = __builtin_convertvector(v, h4);
}

// bucket histogram over dst + last-block-tail exclusive scan.
// done = &bucketCnt[768] (untouched by hist: only slots <293 are written).
__global__ void k_binhistscan(const int* __restrict__ col, int* __restrict__ bucketCnt,
                              int* __restrict__ bucketPtr, int* __restrict__ bucketCur,
                              int NB, long E, int* __restrict__ rowptrN) {
    __shared__ int h[BNODES];
    __shared__ int isLast;
    for (int i = threadIdx.x; i < BNODES; i += BLK) h[i] = 0;
    __syncthreads();
    const long stride = (long)gridDim.x * BLK;
    for (long e = (long)blockIdx.x * BLK + threadIdx.x; e < E; e += stride)
        atomicAdd(&h[col[e] >> BSHIFT], 1);
    __syncthreads();
    for (int i = threadIdx.x; i < BNODES; i += BLK)
        if (h[i]) atomicAdd(&bucketCnt[i], h[i]);

    // last finished block performs the scan (device-scope atomics published
    // above; __threadfence orders them before the done-counter increment).
    __threadfence();
    if (threadIdx.x == 0)
        isLast = (atomicAdd(&bucketCnt[768], 1) == (int)gridDim.x - 1);
    __syncthreads();
    if (!isLast) return;

    int t = threadIdx.x;
    int v0 = (2 * t < NB) ? atomicAdd(&bucketCnt[2 * t], 0) : 0;
    int v1 = (2 * t + 1 < NB) ? atomicAdd(&bucketCnt[2 * t + 1], 0) : 0;
    h[t] = v0 + v1;
    __syncthreads();
    for (int off = 1; off < BLK; off <<= 1) {
        int mine = h[t];
        int add = (t >= off) ? h[t - off] : 0;
        __syncthreads();
        h[t] = mine + add;
        __syncthreads();
    }
    int excl = (t > 0) ? h[t - 1] : 0;
    if (2 * t < NB)     { bucketPtr[2 * t] = excl;          bucketCur[2 * t] = excl; }
    if (2 * t + 1 < NB) { bucketPtr[2 * t + 1] = excl + v0; bucketCur[2 * t + 1] = excl + v0; }
    if (t == 0) { bucketPtr[NB] = (int)E; *rowptrN = (int)E; }
}

// scatter (src,dst) pairs into bucket-grouped staging (CU-local write runs).
__global__ void k_binscatter(const int* __restrict__ row, const int* __restrict__ col,
                             int* __restrict__ bucketCur, int2* __restrict__ staging,
                             long E) {
    __shared__ int h[BNODES];
    __shared__ int gb[BNODES];
    __shared__ int lc[BNODES];
    const long e0 = (long)blockIdx.x * EB;
    const int n = (int)((E - e0 < EB) ? (E - e0) : EB);
    for (int i = threadIdx.x; i < BNODES; i += BLK) h[i] = 0;
    __syncthreads();
    for (int i = threadIdx.x; i < n; i += BLK)
        atomicAdd(&h[col[e0 + i] >> BSHIFT], 1);
    __syncthreads();
    for (int b = threadIdx.x; b < BNODES; b += BLK) {
        int c = h[b];
        gb[b] = c ? atomicAdd(&bucketCur[b], c) : 0;
        lc[b] = 0;
    }
    __syncthreads();
    for (int i = threadIdx.x; i < n; i += BLK) {
        int c = col[e0 + i];
        int r = row[e0 + i];
        int b = c >> BSHIFT;
        int pos = gb[b] + atomicAdd(&lc[b], 1);
        staging[pos] = make_int2(r, c);
    }
}

// one block per bucket: count/scan -> rowptr/dinv -> place src into CSR;
// fused: scale z0 rows of this bucket by dinv.
__global__ void k_bucket(const int2* __restrict__ staging, const int* __restrict__ bucketPtr,
                         int* __restrict__ edges, int* __restrict__ rowptr,
                         float* __restrict__ dinv, _Float16* __restrict__ z0, long N) {
    __shared__ int cnt[BNODES];
    __shared__ int cur[BNODES];
    __shared__ float dnv[BNODES];
    __shared__ int lds[BLK];
    const int b = blockIdx.x;
    const long lo = (long)b << BSHIFT;
    const int R = (int)(((N - lo) < BNODES) ? (N - lo) : BNODES);
    const int beg = bucketPtr[b];
    const int end = bucketPtr[b + 1];
    const int t = threadIdx.x;

    for (int i = t; i < BNODES; i += BLK) cnt[i] = 0;
    __syncthreads();
    for (int e = beg + t; e < end; e += BLK)
        atomicAdd(&cnt[staging[e].y - (int)lo], 1);
    __syncthreads();

    int v0 = cnt[2 * t];
    int v1 = cnt[2 * t + 1];
    lds[t] = v0 + v1;
    __syncthreads();
    for (int off = 1; off < BLK; off <<= 1) {
        int mine = lds[t];
        int add = (t >= off) ? lds[t - off] : 0;
        __syncthreads();
        lds[t] = mine + add;
        __syncthreads();
    }
    int excl = (t > 0) ? lds[t - 1] : 0;
    int e0 = beg + excl;
    int e1 = e0 + v0;
    cur[2 * t] = e0;
    cur[2 * t + 1] = e1;
    dnv[2 * t] = (v0 > 0) ? rsqrtf((float)v0) : 0.0f;
    dnv[2 * t + 1] = (v1 > 0) ? rsqrtf((float)v1) : 0.0f;
    if (2 * t < R)     { rowptr[lo + 2 * t] = e0;     dinv[lo + 2 * t] = dnv[2 * t]; }
    if (2 * t + 1 < R) { rowptr[lo + 2 * t + 1] = e1; dinv[lo + 2 * t + 1] = dnv[2 * t + 1]; }
    __syncthreads();

    for (int e = beg + t; e < end; e += BLK) {
        int2 p = staging[e];
        int pos = atomicAdd(&cur[p.y - (int)lo], 1);
        edges[pos] = p.x;
    }
    for (int i = t; i < R * 16; i += BLK) {
        int nloc = i >> 4;
        int q = i & 15;
        float d = dnv[nloc];
        h4* p = (h4*)(z0 + (lo + nloc) * DIMH) + q;
        *p = __builtin_convertvector(cvt4(*p) * d, h4);
    }
}

// edge-sum core: 8 lanes per dst node, lane owns 8 dims (16 B fp16 slice).
// One shuffle + one dwordx4 load per edge per lane; unroll 8 = one full
// chunk for the mean-degree-8 node.
__device__ inline f8 edge_sum(const _Float16* __restrict__ cur,
                              const int* __restrict__ edges,
                              int beg, int end, int q) {
    f8 s  = {0.f, 0.f, 0.f, 0.f, 0.f, 0.f, 0.f, 0.f};
    f8 t2 = {0.f, 0.f, 0.f, 0.f, 0.f, 0.f, 0.f, 0.f};
    for (int base = beg; base < end; base += 8) {
        int me = base + q;
        int psrc = (me < end) ? edges[me] : 0;
        int n = end - base;
        if (n > 8) n = 8;
        if (n == 8) {
            int a0 = __shfl(psrc, 0, 8);
            int a1 = __shfl(psrc, 1, 8);
            int a2 = __shfl(psrc, 2, 8);
            int a3 = __shfl(psrc, 3, 8);
            int a4 = __shfl(psrc, 4, 8);
            int a5 = __shfl(psrc, 5, 8);
            int a6 = __shfl(psrc, 6, 8);
            int a7 = __shfl(psrc, 7, 8);
            h8 v0 = ((const h8*)(cur + (long)a0 * DIMH))[q];
            h8 v1 = ((const h8*)(cur + (long)a1 * DIMH))[q];
            h8 v2 = ((const h8*)(cur + (long)a2 * DIMH))[q];
            h8 v3 = ((const h8*)(cur + (long)a3 * DIMH))[q];
            h8 v4 = ((const h8*)(cur + (long)a4 * DIMH))[q];
            h8 v5 = ((const h8*)(cur + (long)a5 * DIMH))[q];
            h8 v6 = ((const h8*)(cur + (long)a6 * DIMH))[q];
            h8 v7 = ((const h8*)(cur + (long)a7 * DIMH))[q];
            s  += cvt8(v0); t2 += cvt8(v1); s  += cvt8(v2); t2 += cvt8(v3);
            s  += cvt8(v4); t2 += cvt8(v5); s  += cvt8(v6); t2 += cvt8(v7);
        } else {
            int j = 0;
            for (; j + 4 <= n; j += 4) {
                int a0 = __shfl(psrc, j + 0, 8);
                int a1 = __shfl(psrc, j + 1, 8);
                int a2 = __shfl(psrc, j + 2, 8);
                int a3 = __shfl(psrc, j + 3, 8);
                h8 v0 = ((const h8*)(cur + (long)a0 * DIMH))[q];
                h8 v1 = ((const h8*)(cur + (long)a1 * DIMH))[q];
                h8 v2 = ((const h8*)(cur + (long)a2 * DIMH))[q];
                h8 v3 = ((const h8*)(cur + (long)a3 * DIMH))[q];
                s  += cvt8(v0); t2 += cvt8(v1); s += cvt8(v2); t2 += cvt8(v3);
            }
            for (; j < n; ++j) {
                int a = __shfl(psrc, j, 8);
                s += cvt8(((const h8*)(cur + (long)a * DIMH))[q]);
            }
        }
    }
    return s + t2;
}

// layers 1..3: z_next = fp16(dinv^2 * sum z[src]), 8 lanes/node.
__global__ void __launch_bounds__(BLK)
k_gather(const _Float16* __restrict__ cur, _Float16* __restrict__ nxt,
         const float* __restrict__ dinv,
         const int* __restrict__ rowptr, const int* __restrict__ edges, long N) {
    long g = (long)blockIdx.x * BLK + threadIdx.x;
    if (g >= N * 8) return;
    long node = g >> 3;
    int q = (int)(g & 7);
    f8 s = edge_sum(cur, edges, rowptr[node], rowptr[node + 1], q);
    float d = dinv[node];
    ((h8*)(nxt + node * DIMH))[q] = __builtin_convertvector(s * (d * d), h8);
}

// layer 4 fused with final accumulate (algebra verified r9/r10):
//   z4 = dinv^2 * sum z3[src]   (in-register)
//   acc = emb0/25 + (z1+z2+z3+z4) * sqrtdeg/25     (pure write)
__global__ void __launch_bounds__(BLK)
k_g4final(const float* __restrict__ uemb, const float* __restrict__ iemb,
          const _Float16* __restrict__ z1, const _Float16* __restrict__ z2,
          const _Float16* __restrict__ z3,
          const float* __restrict__ dinv,
          const int* __restrict__ rowptr, const int* __restrict__ edges,
          float* __restrict__ acc, long uElems, long N) {
    long g = (long)blockIdx.x * BLK + threadIdx.x;
    if (g >= N * 8) return;
    long node = g >> 3;
    int q = (int)(g & 7);
    f8 s = edge_sum(z3, edges, rowptr[node], rowptr[node + 1], q);
    float d = dinv[node];
    long off = node * DIMH + q * 8;
    f8 z4 = s * (d * d);
    f8 zs = cvt8(*(const h8*)(z1 + off)) + cvt8(*(const h8*)(z2 + off))
          + cvt8(*(const h8*)(z3 + off)) + z4;
    float f = (d > 0.f) ? (1.0f / d) * (1.0f / 25.0f) : 0.f;
    f8 e0 = (off < uElems) ? *(const f8*)(uemb + off)
                           : *(const f8*)(iemb + (off - uElems));
    *(f8*)(acc + off) = e0 * (1.0f / 25.0f) + zs * f;
}

// ---------------------------------------------------------------------------
extern "C" void kernel_launch(void* const* d_in, const int* in_sizes, int n_in,
                              void* d_out, int out_size, void* d_ws, size_t ws_size,
                              hipStream_t stream) {
    const float* uemb = (const float*)d_in[0];
    const float* iemb = (const float*)d_in[1];
    const int*   edge = (const int*)d_in[2];

    const long uElems = in_sizes[0];          // 100000*64
    const long iElems = in_sizes[1];          // 50000*64
    const long E      = in_sizes[2] / 2;      // 1200000
    const long total  = uElems + iElems;      // N*64
    const long N      = total / DIMH;         // 150000

    const int* row = edge;      // edge_index[0] = src
    const int* col = edge + E;  // edge_index[1] = dst

    float* acc = (float*)d_out;
    const int NB = (int)((N + BNODES - 1) >> BSHIFT);   // 293 buckets

    // workspace layout (all bases 256B-aligned)
    const long Npad = (N + 63) & ~63L;
    const long Epad = (E + 63) & ~63L;
    int*      rowptr    = (int*)d_ws;                 // N+1 ints
    float*    dinv      = (float*)(rowptr + Npad + 64);
    int*      edges     = (int*)(dinv + Npad);        // E src indices
    int*      bucketCnt = edges + Epad;               // 1024 (slot 768 = done)
    int*      bucketPtr = bucketCnt + 1024;           // 1024 (NB+1 used)
    int*      bucketCur = bucketPtr + 1024;           // 1024
    _Float16* z0        = (_Float16*)(bucketCur + 1024); // N*64 fp16
    _Float16* z1        = z0 + total;
    _Float16* z2        = z1 + total;
    _Float16* z3        = z2 + total;
    int2*     staging   = (int2*)z1;   // E pairs; consumed by k_bucket before
                                       // gather-1 writes z1 (same stream)

    const long total4 = total / 4;
    const int gInit = (int)((total4 + BLK - 1) / BLK);
    k_init<<<gInit, BLK, 0, stream>>>(uemb, iemb, z0, bucketCnt, uElems, total);
    k_binhistscan<<<HISTGRID, BLK, 0, stream>>>(col, bucketCnt, bucketPtr, bucketCur,
                                                NB, E, rowptr + N);
    k_binscatter<<<(int)((E + EB - 1) / EB), BLK, 0, stream>>>(row, col, bucketCur,
                                                               staging, E);
    k_bucket<<<NB, BLK, 0, stream>>>(staging, bucketPtr, edges, rowptr, dinv, z0, N);

    const int gGather = (int)((N * 8 + BLK - 1) / BLK);
    k_gather<<<gGather, BLK, 0, stream>>>(z0, z1, dinv, rowptr, edges, N);
    k_gather<<<gGather, BLK, 0, stream>>>(z1, z2, dinv, rowptr, edges, N);
    k_gather<<<gGather, BLK, 0, stream>>>(z2, z3, dinv, rowptr, edges, N);
    k_g4final<<<gGather, BLK, 0, stream>>>(uemb, iemb, z1, z2, z3, dinv, rowptr,
                                           edges, acc, uElems, N);
}